// Round 2
// baseline (660.351 us; speedup 1.0000x reference)
//
#include <hip/hip_runtime.h>
#include <stdint.h>

#define B_ 8
#define T_ 4096
#define D_ 1024
#define H_ 1024
#define M_ (B_*T_)   /* 32768 */
#define K_ D_
#define N_ H_
#define TC 64
#define NC (T_/TC)   /* 64 */

typedef short short8 __attribute__((ext_vector_type(8)));
typedef float f32x4 __attribute__((ext_vector_type(4)));

__device__ __forceinline__ float bf2f(unsigned short u) {
    union { unsigned int i; float f; } x; x.i = ((unsigned int)u) << 16; return x.f;
}
__device__ __forceinline__ unsigned short f2bf(float f) {
    union { float f; unsigned int i; } x; x.f = f;
    unsigned int u = x.i;
    unsigned int r = u + 0x7fffu + ((u >> 16) & 1u);
    return (unsigned short)(r >> 16);
}
__device__ __forceinline__ void gld_lds16(const unsigned short* g, unsigned short* l) {
    __builtin_amdgcn_global_load_lds(
        (const __attribute__((address_space(1))) void*)(const void*)g,
        (__attribute__((address_space(3))) void*)(void*)l, 16, 0, 0);
}
__device__ __forceinline__ float gfun(float x) {
    return x >= 0.f ? x + 0.5f : 1.f / (1.f + __expf(-x));
}

// ---------------- fused fp32 -> bf16 convert (x, W_z, W_h) ----------------
__global__ void cvt3_kernel(const float* __restrict__ x, const float* __restrict__ wz,
                            const float* __restrict__ wh,
                            unsigned short* __restrict__ xb, unsigned short* __restrict__ wzb,
                            unsigned short* __restrict__ whb) {
    const int n4x = M_ * K_ / 4;
    const int n4w = N_ * K_ / 4;
    const int total = n4x + 2 * n4w;
    int i = blockIdx.x * blockDim.x + threadIdx.x;
    const int stride = gridDim.x * blockDim.x;
    for (; i < total; i += stride) {
        const float* s; unsigned short* d; int j;
        if (i < n4x)            { s = x;  d = xb;  j = i; }
        else if (i < n4x + n4w) { s = wz; d = wzb; j = i - n4x; }
        else                    { s = wh; d = whb; j = i - n4x - n4w; }
        float4 v = ((const float4*)s)[j];
        ushort4 o;
        o.x = f2bf(v.x); o.y = f2bf(v.y); o.z = f2bf(v.z); o.w = f2bf(v.w);
        ((ushort4*)d)[j] = o;
    }
}

// ---------------- dual bf16 MFMA GEMM: Kz = X*Wz^T + bz ; Kh = X*Wh^T + bh ----------------
// 128x128 tile, BK=32, 4 waves (2x2), shared A-tile, two B-tiles, 32 MFMAs/wave/iter.
// LDS write layout forced linear by global_load_lds; bank conflicts broken by
// permuting the GLOBAL k-chunk each lane fetches: slot s of row R holds global
// chunk s ^ h(R), h(R) = ((R&15)>>1)&3. Read applies same permutation -> 2-way (free).
__global__ __launch_bounds__(256) void gemm2_kernel(
    const unsigned short* __restrict__ Xb,
    const unsigned short* __restrict__ Wzb,
    const unsigned short* __restrict__ Whb,
    const float* __restrict__ bz, const float* __restrict__ bh,
    unsigned short* __restrict__ KzOut, unsigned short* __restrict__ KhOut)
{
    __shared__ __align__(16) unsigned short lds_a[128 * 32];
    __shared__ __align__(16) unsigned short lds_bz[128 * 32];
    __shared__ __align__(16) unsigned short lds_bh[128 * 32];

    const int bm = blockIdx.x;
    const int bn = blockIdx.y;
    const int tid = threadIdx.x;
    const int w = tid >> 6, lane = tid & 63;
    const int wm = w >> 1, wn = w & 1;

    f32x4 accz[4][4], acch[4][4];
#pragma unroll
    for (int i = 0; i < 4; i++)
#pragma unroll
        for (int j = 0; j < 4; j++) {
            accz[i][j] = (f32x4){0.f, 0.f, 0.f, 0.f};
            acch[i][j] = (f32x4){0.f, 0.f, 0.f, 0.f};
        }

    // staging: row within 16-row group = lane>>2; global chunk = (lane&3) ^ h(row)
    const int kcs = (((lane & 3) ^ ((lane >> 3) & 3))) * 8;
    const int r0 = (w * 2 + 0) * 16 + (lane >> 2);
    const int r1 = (w * 2 + 1) * 16 + (lane >> 2);
    const unsigned short* gA0 = Xb  + (size_t)(bm * 128 + r0) * K_ + kcs;
    const unsigned short* gA1 = Xb  + (size_t)(bm * 128 + r1) * K_ + kcs;
    const unsigned short* gZ0 = Wzb + (size_t)(bn * 128 + r0) * K_ + kcs;
    const unsigned short* gZ1 = Wzb + (size_t)(bn * 128 + r1) * K_ + kcs;
    const unsigned short* gH0 = Whb + (size_t)(bn * 128 + r0) * K_ + kcs;
    const unsigned short* gH1 = Whb + (size_t)(bn * 128 + r1) * K_ + kcs;
    unsigned short* la0 = &lds_a [(w * 2 + 0) * 512];
    unsigned short* la1 = &lds_a [(w * 2 + 1) * 512];
    unsigned short* lz0 = &lds_bz[(w * 2 + 0) * 512];
    unsigned short* lz1 = &lds_bz[(w * 2 + 1) * 512];
    unsigned short* lh0 = &lds_bh[(w * 2 + 0) * 512];
    unsigned short* lh1 = &lds_bh[(w * 2 + 1) * 512];

    // fragment read: row m = lane&15 (within tile), global chunk q = lane>>4
    // LDS slot = q ^ h(m), h(m) = ((m>>1)&3) -> 2-way bank aliasing only
    const int sw = ((lane >> 4) ^ ((lane >> 1) & 3)) * 8;
    const unsigned short* ra  = &lds_a [(wm * 64 + (lane & 15)) * 32 + sw];
    const unsigned short* rbz = &lds_bz[(wn * 64 + (lane & 15)) * 32 + sw];
    const unsigned short* rbh = &lds_bh[(wn * 64 + (lane & 15)) * 32 + sw];

    for (int k0 = 0; k0 < K_; k0 += 32) {
        __syncthreads();   // prior iter ds_reads done before overwrite
        gld_lds16(gA0 + k0, la0);
        gld_lds16(gA1 + k0, la1);
        gld_lds16(gZ0 + k0, lz0);
        gld_lds16(gZ1 + k0, lz1);
        gld_lds16(gH0 + k0, lh0);
        gld_lds16(gH1 + k0, lh1);
        __syncthreads();   // drains vmcnt before ds_read

        short8 af[4], bzf[4], bhf[4];
#pragma unroll
        for (int im = 0; im < 4; im++) af[im]  = *(const short8*)(ra  + im * 16 * 32);
#pragma unroll
        for (int in = 0; in < 4; in++) bzf[in] = *(const short8*)(rbz + in * 16 * 32);
#pragma unroll
        for (int in = 0; in < 4; in++) bhf[in] = *(const short8*)(rbh + in * 16 * 32);
#pragma unroll
        for (int im = 0; im < 4; im++)
#pragma unroll
            for (int in = 0; in < 4; in++) {
                accz[im][in] = __builtin_amdgcn_mfma_f32_16x16x32_bf16(af[im], bzf[in], accz[im][in], 0, 0, 0);
                acch[im][in] = __builtin_amdgcn_mfma_f32_16x16x32_bf16(af[im], bhf[in], acch[im][in], 0, 0, 0);
            }
    }

    // epilogue: C/D map col=lane&15, row=(lane>>4)*4+r ; add bias, store bf16
#pragma unroll
    for (int in = 0; in < 4; in++) {
        const int col = bn * 128 + wn * 64 + in * 16 + (lane & 15);
        const float bbz = bz[col];
        const float bbh = bh[col];
#pragma unroll
        for (int im = 0; im < 4; im++) {
            const int row0 = bm * 128 + wm * 64 + im * 16 + (lane >> 4) * 4;
#pragma unroll
            for (int r = 0; r < 4; r++) {
                KzOut[(size_t)(row0 + r) * N_ + col] = f2bf(accz[im][in][r] + bbz);
                KhOut[(size_t)(row0 + r) * N_ + col] = f2bf(acch[im][in][r] + bbh);
            }
        }
    }
}

// ---------------- scan A: per-chunk affine aggregates (F = prod f, V) ----------------
__global__ __launch_bounds__(256) void scanA_kernel(const unsigned short* __restrict__ Kz,
                                                    const unsigned short* __restrict__ Kh,
                                                    float* __restrict__ Fc, float* __restrict__ Vc)
{
    const int c = blockIdx.x, b = blockIdx.y;
    const int h = threadIdx.x * 4;
    size_t base = ((size_t)(b * T_ + c * TC)) * H_ + h;
    float F[4] = {1.f, 1.f, 1.f, 1.f}, V[4] = {0.f, 0.f, 0.f, 0.f};
    for (int t = 0; t < TC; t++) {
        ushort4 kz4 = *(const ushort4*)(Kz + base);
        ushort4 kh4 = *(const ushort4*)(Kh + base);
        base += H_;
        float kzf[4] = {bf2f(kz4.x), bf2f(kz4.y), bf2f(kz4.z), bf2f(kz4.w)};
        float khf[4] = {bf2f(kh4.x), bf2f(kh4.y), bf2f(kh4.z), bf2f(kh4.w)};
#pragma unroll
        for (int j = 0; j < 4; j++) {
            float f = 1.f / (1.f + __expf(kzf[j]));   // 1 - sigmoid(kz)
            float v = (1.f - f) * gfun(khf[j]);       // sigmoid(kz)*g(kh)
            V[j] = f * V[j] + v;
            F[j] *= f;
        }
    }
    size_t o = ((size_t)(b * NC + c)) * H_ + h;
    *(float4*)(Fc + o) = make_float4(F[0], F[1], F[2], F[3]);
    *(float4*)(Vc + o) = make_float4(V[0], V[1], V[2], V[3]);
}

// ---------------- scan B: serial scan over chunk aggregates; writes t=0 row ----------------
__global__ __launch_bounds__(256) void scanB_kernel(const float* __restrict__ h0,
                                                    const float* __restrict__ Fc,
                                                    const float* __restrict__ Vc,
                                                    float* __restrict__ Carry,
                                                    float* __restrict__ Out)
{
    const int b = blockIdx.x;
    const int h = threadIdx.x * 4;
    float cy[4];
#pragma unroll
    for (int j = 0; j < 4; j++) cy[j] = gfun(h0[(size_t)b * H_ + h + j]);
    *(float4*)(Out + (size_t)b * (T_ + 1) * H_ + h) = make_float4(cy[0], cy[1], cy[2], cy[3]);
    for (int c = 0; c < NC; c++) {
        size_t o = ((size_t)(b * NC + c)) * H_ + h;
        *(float4*)(Carry + o) = make_float4(cy[0], cy[1], cy[2], cy[3]);
        float4 F4 = *(const float4*)(Fc + o);
        float4 V4 = *(const float4*)(Vc + o);
        cy[0] = F4.x * cy[0] + V4.x;
        cy[1] = F4.y * cy[1] + V4.y;
        cy[2] = F4.z * cy[2] + V4.z;
        cy[3] = F4.w * cy[3] + V4.w;
    }
}

// ---------------- scan C: replay chunks with incoming carry, write outputs ----------------
__global__ __launch_bounds__(256) void scanC_kernel(const unsigned short* __restrict__ Kz,
                                                    const unsigned short* __restrict__ Kh,
                                                    const float* __restrict__ Carry,
                                                    float* __restrict__ Out)
{
    const int c = blockIdx.x, b = blockIdx.y;
    const int h = threadIdx.x * 4;
    float cy[4];
    {
        float4 c4 = *(const float4*)(Carry + ((size_t)(b * NC + c)) * H_ + h);
        cy[0] = c4.x; cy[1] = c4.y; cy[2] = c4.z; cy[3] = c4.w;
    }
    size_t base = ((size_t)(b * T_ + c * TC)) * H_ + h;
    size_t ob = ((size_t)(b * (T_ + 1) + c * TC + 1)) * H_ + h;
    for (int t = 0; t < TC; t++) {
        ushort4 kz4 = *(const ushort4*)(Kz + base);
        ushort4 kh4 = *(const ushort4*)(Kh + base);
        base += H_;
        float kzf[4] = {bf2f(kz4.x), bf2f(kz4.y), bf2f(kz4.z), bf2f(kz4.w)};
        float khf[4] = {bf2f(kh4.x), bf2f(kh4.y), bf2f(kh4.z), bf2f(kh4.w)};
#pragma unroll
        for (int j = 0; j < 4; j++) {
            float f = 1.f / (1.f + __expf(kzf[j]));
            float v = (1.f - f) * gfun(khf[j]);
            cy[j] = f * cy[j] + v;
        }
        *(float4*)(Out + ob) = make_float4(cy[0], cy[1], cy[2], cy[3]);
        ob += H_;
    }
}

extern "C" void kernel_launch(void* const* d_in, const int* in_sizes, int n_in,
                              void* d_out, int out_size, void* d_ws, size_t ws_size,
                              hipStream_t stream)
{
    const float* x  = (const float*)d_in[0];
    const float* h0 = (const float*)d_in[1];
    const float* Wz = (const float*)d_in[2];
    const float* bz = (const float*)d_in[3];
    const float* Wh = (const float*)d_in[4];
    const float* bh = (const float*)d_in[5];
    float* out = (float*)d_out;

    char* ws = (char*)d_ws;
    unsigned short* xb  = (unsigned short*)ws; ws += (size_t)M_ * K_ * 2;   // 64 MiB
    unsigned short* wzb = (unsigned short*)ws; ws += (size_t)N_ * K_ * 2;   // 2 MiB
    unsigned short* whb = (unsigned short*)ws; ws += (size_t)N_ * K_ * 2;   // 2 MiB
    unsigned short* kz  = (unsigned short*)ws; ws += (size_t)M_ * N_ * 2;   // 64 MiB
    unsigned short* kh  = (unsigned short*)ws; ws += (size_t)M_ * N_ * 2;   // 64 MiB
    float* Fc    = (float*)ws; ws += (size_t)B_ * NC * H_ * 4;              // 2 MiB
    float* Vc    = (float*)ws; ws += (size_t)B_ * NC * H_ * 4;              // 2 MiB
    float* Carry = (float*)ws; ws += (size_t)B_ * NC * H_ * 4;              // 2 MiB

    cvt3_kernel<<<3072, 256, 0, stream>>>(x, Wz, Wh, xb, wzb, whb);

    dim3 gg(M_ / 128, N_ / 128);
    gemm2_kernel<<<gg, 256, 0, stream>>>(xb, wzb, whb, bz, bh, kz, kh);

    scanA_kernel<<<dim3(NC, B_), 256, 0, stream>>>(kz, kh, Fc, Vc);
    scanB_kernel<<<B_, 256, 0, stream>>>(h0, Fc, Vc, Carry, out);
    scanC_kernel<<<dim3(NC, B_), 256, 0, stream>>>(kz, kh, Carry, out);
}

// Round 3
// 506.311 us; speedup vs baseline: 1.3042x; 1.3042x over previous
//
#include <hip/hip_runtime.h>
#include <stdint.h>

#define B_ 8
#define T_ 4096
#define D_ 1024
#define H_ 1024
#define M_ (B_*T_)   /* 32768 */
#define K_ D_
#define N_ H_
#define TC 64
#define NC (T_/TC)   /* 64 */

typedef short short8 __attribute__((ext_vector_type(8)));
typedef float f32x4 __attribute__((ext_vector_type(4)));
typedef unsigned short ushort8v __attribute__((ext_vector_type(8)));

__device__ __forceinline__ float bf2f(unsigned short u) {
    union { unsigned int i; float f; } x; x.i = ((unsigned int)u) << 16; return x.f;
}
__device__ __forceinline__ unsigned short f2bf(float f) {
    union { float f; unsigned int i; } x; x.f = f;
    unsigned int u = x.i;
    unsigned int r = u + 0x7fffu + ((u >> 16) & 1u);
    return (unsigned short)(r >> 16);
}
__device__ __forceinline__ void gld_lds16(const unsigned short* g, unsigned short* l) {
    __builtin_amdgcn_global_load_lds(
        (const __attribute__((address_space(1))) void*)(const void*)g,
        (__attribute__((address_space(3))) void*)(void*)l, 16, 0, 0);
}
__device__ __forceinline__ float gfun(float x) {
    return x >= 0.f ? x + 0.5f : 1.f / (1.f + __expf(-x));
}

// ---------------- fp32 -> bf16 convert ----------------
__global__ void cvt_kernel(const float* __restrict__ src, unsigned short* __restrict__ dst, int n4) {
    int i = blockIdx.x * blockDim.x + threadIdx.x;
    const int stride = gridDim.x * blockDim.x;
    for (; i < n4; i += stride) {
        float4 v = ((const float4*)src)[i];
        ushort4 o;
        o.x = f2bf(v.x); o.y = f2bf(v.y); o.z = f2bf(v.z); o.w = f2bf(v.w);
        ((ushort4*)dst)[i] = o;
    }
}

// ---------------- bf16 MFMA GEMM: K = X[M,K] * W^T[N,K] + bias, packed output ----------------
// 128x128 tile, BK=32, 4 waves (2x2), 4x4 16x16x32 MFMAs/wave.
// LDS bank conflicts broken by permuting the GLOBAL k-chunk each lane stages:
// slot s of row R holds chunk s ^ (((R&15)>>1)&3); reads apply the same perm (2-way = free).
// Output layout "t-quad packed": element [m][n] at ((m>>2)*N + n)*4 + (m&3),
// so each lane's 4 acc values (4 consecutive m, fixed n) are one 8B ushort4 store.
__global__ __launch_bounds__(256) void gemm_kernel(
    const unsigned short* __restrict__ Xb,
    const unsigned short* __restrict__ Wzb,
    const unsigned short* __restrict__ Whb,
    const float* __restrict__ bz, const float* __restrict__ bh,
    unsigned short* __restrict__ KzOut, unsigned short* __restrict__ KhOut)
{
    __shared__ __align__(16) unsigned short lds_a[128 * 32];
    __shared__ __align__(16) unsigned short lds_b[128 * 32];

    const int bm = blockIdx.x;
    const int bn = blockIdx.y;
    const int mat = blockIdx.z;
    const unsigned short* Wb = mat ? Whb : Wzb;
    const float* bias = mat ? bh : bz;
    unsigned short* Out = mat ? KhOut : KzOut;

    const int tid = threadIdx.x;
    const int w = tid >> 6, lane = tid & 63;
    const int wm = w >> 1, wn = w & 1;

    f32x4 acc[4][4];
#pragma unroll
    for (int i = 0; i < 4; i++)
#pragma unroll
        for (int j = 0; j < 4; j++) acc[i][j] = (f32x4){0.f, 0.f, 0.f, 0.f};

    // staging: row within 16-row group = lane>>2; global chunk = (lane&3) ^ ((lane>>3)&3)
    const int kcs = ((lane & 3) ^ ((lane >> 3) & 3)) * 8;
    const int r0 = (w * 2 + 0) * 16 + (lane >> 2);
    const int r1 = (w * 2 + 1) * 16 + (lane >> 2);
    const unsigned short* gA0 = Xb + (size_t)(bm * 128 + r0) * K_ + kcs;
    const unsigned short* gA1 = Xb + (size_t)(bm * 128 + r1) * K_ + kcs;
    const unsigned short* gB0 = Wb + (size_t)(bn * 128 + r0) * K_ + kcs;
    const unsigned short* gB1 = Wb + (size_t)(bn * 128 + r1) * K_ + kcs;
    unsigned short* la0 = &lds_a[(w * 2 + 0) * 512];
    unsigned short* la1 = &lds_a[(w * 2 + 1) * 512];
    unsigned short* lb0 = &lds_b[(w * 2 + 0) * 512];
    unsigned short* lb1 = &lds_b[(w * 2 + 1) * 512];

    // fragment read: row m = lane&15, chunk q = lane>>4; LDS slot = q ^ ((m>>1)&3)
    const int sw = ((lane >> 4) ^ ((lane >> 1) & 3)) * 8;
    const unsigned short* ra = &lds_a[(wm * 64 + (lane & 15)) * 32 + sw];
    const unsigned short* rb = &lds_b[(wn * 64 + (lane & 15)) * 32 + sw];

    for (int k0 = 0; k0 < K_; k0 += 32) {
        __syncthreads();   // prior iter ds_reads done before overwrite
        gld_lds16(gA0 + k0, la0);
        gld_lds16(gA1 + k0, la1);
        gld_lds16(gB0 + k0, lb0);
        gld_lds16(gB1 + k0, lb1);
        __syncthreads();   // drains vmcnt before ds_read

        short8 af[4], bfr[4];
#pragma unroll
        for (int im = 0; im < 4; im++) af[im] = *(const short8*)(ra + im * 16 * 32);
#pragma unroll
        for (int in = 0; in < 4; in++) bfr[in] = *(const short8*)(rb + in * 16 * 32);
#pragma unroll
        for (int im = 0; im < 4; im++)
#pragma unroll
            for (int in = 0; in < 4; in++)
                acc[im][in] = __builtin_amdgcn_mfma_f32_16x16x32_bf16(af[im], bfr[in], acc[im][in], 0, 0, 0);
    }

    // epilogue: packed 8B stores. mq = m>>2 is lane-uniform per (im): rows (lane>>4)*4+r.
#pragma unroll
    for (int in = 0; in < 4; in++) {
        const int n = bn * 128 + wn * 64 + in * 16 + (lane & 15);
        const float bb = bias[n];
#pragma unroll
        for (int im = 0; im < 4; im++) {
            const int mq = bm * 32 + wm * 16 + im * 4 + (lane >> 4);
            ushort4 o;
            o.x = f2bf(acc[im][in][0] + bb);
            o.y = f2bf(acc[im][in][1] + bb);
            o.z = f2bf(acc[im][in][2] + bb);
            o.w = f2bf(acc[im][in][3] + bb);
            *(ushort4*)(Out + ((size_t)mq * N_ + n) * 4) = o;
        }
    }
}

// Packed-layout accessor note for scans:
// K[m][n] lives at ((m>>2)*N + n)*4 + (m&3), m = b*T + t.
// A thread owning columns hb..hb+3 loads, per t-quad q, two 16B vectors:
//   base = ((b*1024 + (t0>>2))*N + hb)*4 ; v0 = cols hb,hb+1 ; v1 = cols hb+2,hb+3
//   value(col j, t0+r) = v[j>>1][(j&1)*4 + r]

// ---------------- scan A: per-chunk affine aggregates (F = prod f, V) ----------------
__global__ __launch_bounds__(256) void scanA_kernel(const unsigned short* __restrict__ Kz,
                                                    const unsigned short* __restrict__ Kh,
                                                    float* __restrict__ Fc, float* __restrict__ Vc)
{
    const int c = blockIdx.x, b = blockIdx.y;
    const int hb = threadIdx.x * 4;
    float F[4] = {1.f, 1.f, 1.f, 1.f}, V[4] = {0.f, 0.f, 0.f, 0.f};
    size_t base = ((size_t)(b * 1024 + c * (TC / 4)) * N_ + hb) * 4;
    for (int q = 0; q < TC / 4; q++) {
        ushort8v z0 = *(const ushort8v*)(Kz + base);
        ushort8v z1 = *(const ushort8v*)(Kz + base + 8);
        ushort8v h0v = *(const ushort8v*)(Kh + base);
        ushort8v h1v = *(const ushort8v*)(Kh + base + 8);
        base += (size_t)N_ * 4;
#pragma unroll
        for (int r = 0; r < 4; r++) {
            float kzf[4] = {bf2f(z0[r]), bf2f(z0[4 + r]), bf2f(z1[r]), bf2f(z1[4 + r])};
            float khf[4] = {bf2f(h0v[r]), bf2f(h0v[4 + r]), bf2f(h1v[r]), bf2f(h1v[4 + r])};
#pragma unroll
            for (int j = 0; j < 4; j++) {
                float f = 1.f / (1.f + __expf(kzf[j]));   // 1 - sigmoid(kz)
                float v = (1.f - f) * gfun(khf[j]);       // sigmoid(kz)*g(kh)
                V[j] = f * V[j] + v;
                F[j] *= f;
            }
        }
    }
    size_t o = ((size_t)(b * NC + c)) * H_ + hb;
    *(float4*)(Fc + o) = make_float4(F[0], F[1], F[2], F[3]);
    *(float4*)(Vc + o) = make_float4(V[0], V[1], V[2], V[3]);
}

// ---------------- scan B: serial scan over chunk aggregates; writes t=0 row ----------------
__global__ __launch_bounds__(256) void scanB_kernel(const float* __restrict__ h0,
                                                    const float* __restrict__ Fc,
                                                    const float* __restrict__ Vc,
                                                    float* __restrict__ Carry,
                                                    float* __restrict__ Out)
{
    const int b = blockIdx.x;
    const int h = threadIdx.x * 4;
    float cy[4];
#pragma unroll
    for (int j = 0; j < 4; j++) cy[j] = gfun(h0[(size_t)b * H_ + h + j]);
    *(float4*)(Out + (size_t)b * (T_ + 1) * H_ + h) = make_float4(cy[0], cy[1], cy[2], cy[3]);
    for (int c = 0; c < NC; c++) {
        size_t o = ((size_t)(b * NC + c)) * H_ + h;
        *(float4*)(Carry + o) = make_float4(cy[0], cy[1], cy[2], cy[3]);
        float4 F4 = *(const float4*)(Fc + o);
        float4 V4 = *(const float4*)(Vc + o);
        cy[0] = F4.x * cy[0] + V4.x;
        cy[1] = F4.y * cy[1] + V4.y;
        cy[2] = F4.z * cy[2] + V4.z;
        cy[3] = F4.w * cy[3] + V4.w;
    }
}

// ---------------- scan C: replay chunks with incoming carry, write outputs ----------------
__global__ __launch_bounds__(256) void scanC_kernel(const unsigned short* __restrict__ Kz,
                                                    const unsigned short* __restrict__ Kh,
                                                    const float* __restrict__ Carry,
                                                    float* __restrict__ Out)
{
    const int c = blockIdx.x, b = blockIdx.y;
    const int hb = threadIdx.x * 4;
    float cy[4];
    {
        float4 c4 = *(const float4*)(Carry + ((size_t)(b * NC + c)) * H_ + hb);
        cy[0] = c4.x; cy[1] = c4.y; cy[2] = c4.z; cy[3] = c4.w;
    }
    size_t base = ((size_t)(b * 1024 + c * (TC / 4)) * N_ + hb) * 4;
    size_t ob = ((size_t)(b * (T_ + 1) + c * TC + 1)) * H_ + hb;
    for (int q = 0; q < TC / 4; q++) {
        ushort8v z0 = *(const ushort8v*)(Kz + base);
        ushort8v z1 = *(const ushort8v*)(Kz + base + 8);
        ushort8v h0v = *(const ushort8v*)(Kh + base);
        ushort8v h1v = *(const ushort8v*)(Kh + base + 8);
        base += (size_t)N_ * 4;
#pragma unroll
        for (int r = 0; r < 4; r++) {
            float kzf[4] = {bf2f(z0[r]), bf2f(z0[4 + r]), bf2f(z1[r]), bf2f(z1[4 + r])};
            float khf[4] = {bf2f(h0v[r]), bf2f(h0v[4 + r]), bf2f(h1v[r]), bf2f(h1v[4 + r])};
#pragma unroll
            for (int j = 0; j < 4; j++) {
                float f = 1.f / (1.f + __expf(kzf[j]));
                float v = (1.f - f) * gfun(khf[j]);
                cy[j] = f * cy[j] + v;
            }
            *(float4*)(Out + ob) = make_float4(cy[0], cy[1], cy[2], cy[3]);
            ob += H_;
        }
    }
}

extern "C" void kernel_launch(void* const* d_in, const int* in_sizes, int n_in,
                              void* d_out, int out_size, void* d_ws, size_t ws_size,
                              hipStream_t stream)
{
    const float* x  = (const float*)d_in[0];
    const float* h0 = (const float*)d_in[1];
    const float* Wz = (const float*)d_in[2];
    const float* bz = (const float*)d_in[3];
    const float* Wh = (const float*)d_in[4];
    const float* bh = (const float*)d_in[5];
    float* out = (float*)d_out;

    char* ws = (char*)d_ws;
    unsigned short* xb  = (unsigned short*)ws; ws += (size_t)M_ * K_ * 2;   // 64 MiB
    unsigned short* wzb = (unsigned short*)ws; ws += (size_t)N_ * K_ * 2;   // 2 MiB
    unsigned short* whb = (unsigned short*)ws; ws += (size_t)N_ * K_ * 2;   // 2 MiB
    unsigned short* kz  = (unsigned short*)ws; ws += (size_t)M_ * N_ * 2;   // 64 MiB
    unsigned short* kh  = (unsigned short*)ws; ws += (size_t)M_ * N_ * 2;   // 64 MiB
    float* Fc    = (float*)ws; ws += (size_t)B_ * NC * H_ * 4;              // 2 MiB
    float* Vc    = (float*)ws; ws += (size_t)B_ * NC * H_ * 4;              // 2 MiB
    float* Carry = (float*)ws; ws += (size_t)B_ * NC * H_ * 4;              // 2 MiB

    cvt_kernel<<<2048, 256, 0, stream>>>(x, xb, M_ * K_ / 4);
    cvt_kernel<<<256, 256, 0, stream>>>(Wz, wzb, N_ * K_ / 4);
    cvt_kernel<<<256, 256, 0, stream>>>(Wh, whb, N_ * K_ / 4);

    dim3 gg(M_ / 128, N_ / 128, 2);
    gemm_kernel<<<gg, 256, 0, stream>>>(xb, wzb, whb, bz, bh, kz, kh);

    scanA_kernel<<<dim3(NC, B_), 256, 0, stream>>>(kz, kh, Fc, Vc);
    scanB_kernel<<<B_, 256, 0, stream>>>(h0, Fc, Vc, Carry, out);
    scanC_kernel<<<dim3(NC, B_), 256, 0, stream>>>(kz, kh, Carry, out);
}